// Round 19
// baseline (168.178 us; speedup 1.0000x reference)
//
#include <hip/hip_runtime.h>

#define N_NODES 100000
#define N_EDGES 1600000
#define D_IN 32
#define D_HID 16
#define D_OUT 2

// dst bucketing: 128 nodes per bucket.
#define NPB 128
#define NB 782                       // ceil(100000/128)
#define NROWS (NB * NPB)             // 100096 padded feature rows
#define CHUNK 4096
#define BBLOCKS ((N_EDGES + CHUNK - 1) / CHUNK)   // 391

// Padded per-bucket record windows (mean fill 2046, 11 sigma headroom).
#define PBC 2560
#define DUMMY_SRC 100000u            // zeroed xr feature row
#define DUMMY_REC ((127u << 17) | DUMMY_SRC)
#define PAD_ALIGN 16

// Layer-2 acc: 2 lanes/record, ACC2_K records per group, 128 groups/block.
#define ACC2_K 16
#define ACC2_BPB 2                     // 2*128*16 = 4096 slots >= PBC
#define ACC2_BLOCKS (NB * ACC2_BPB)    // 1564

__device__ __forceinline__ unsigned bfr(float x) {   // f32 -> bf16 (RNE)
    unsigned u = __float_as_uint(x);
    return (u + 0x7FFFu + ((u >> 16) & 1u)) >> 16;
}
__device__ __forceinline__ float bfu(unsigned lo16) {
    return __uint_as_float(lo16 << 16);
}

// ---------------------------------------------------------------------------
// Fused bin + node-1 transform with bucket-grouped coalesced write-out:
//  A. LDS histogram of the block's 4096-edge chunk
//  B. node-1 dense transform (overlapped; VALU hides A's latency)
//  C. (wave 0) shuffle-scan cnt -> loff  ||  (waves 1-7) global cursor
//     reservation -> gbase
//  D1. placement: rank each record (LDS atomic), store rec + its final
//      GLOBAL slot (gidx, word-granular — avoids R18's ushort sub-word
//      bank conflicts)
//  D2. linear write-out: recs2[gidx[i]] = sorted[i]; consecutive lanes
//      hit consecutive window slots (runs of ~5.2 records/bucket)
// ---------------------------------------------------------------------------
__global__ __launch_bounds__(512) void k_bin_node1(
    const int* __restrict__ ei, const float* __restrict__ x,
    const float* __restrict__ w_rel, const float* __restrict__ w_root,
    const float* __restrict__ bb,
    unsigned short* __restrict__ xr, float* __restrict__ aggr,
    int* __restrict__ gcur, unsigned* __restrict__ recs2)
{
    __shared__ int cnt[NB];
    __shared__ int lcnt[NB];
    __shared__ int loff[NB];
    __shared__ int gbase[NB];
    __shared__ unsigned sorted[CHUNK];           // 16 KB
    __shared__ int gidx[CHUNK];                  // 16 KB (word-granular)
    __shared__ float s_rel[D_HID * D_IN];
    __shared__ float s_root[D_HID * D_IN];
    __shared__ float s_b[D_HID];
    int blk = blockIdx.x, tid = threadIdx.x;

    for (int i = tid; i < D_HID * D_IN; i += 512) {
        s_rel[i]  = w_rel[i];
        s_root[i] = w_root[i];
    }
    if (tid < D_HID) s_b[tid] = bb[tid];
    for (int i = tid; i < NB; i += 512) { cnt[i] = 0; lcnt[i] = 0; }
    __syncthreads();

    // ---- phase A: histogram ----
    int e0 = blk * CHUNK;
    int e1 = min(e0 + CHUNK, N_EDGES);
    for (int e = e0 + tid; e < e1; e += 512)
        atomicAdd(&cnt[ei[N_EDGES + e] >> 7], 1);

    // ---- phase B: node-1 transform (independent of A) ----
    int node = blk * 512 + tid;                    // 391*512 = 200192 > 100001
    if (node == N_NODES) {                         // dummy zero xr row
        uint4* xp = (uint4*)(xr + (size_t)node * D_HID);
        xp[0] = make_uint4(0, 0, 0, 0);
        xp[1] = make_uint4(0, 0, 0, 0);
    } else if (node < N_NODES) {
        float row[D_IN];
        const float4* xp = (const float4*)(x + (size_t)node * D_IN);
#pragma unroll
        for (int i = 0; i < D_IN / 4; i++) {
            float4 v = xp[i];
            row[4*i+0] = v.x; row[4*i+1] = v.y; row[4*i+2] = v.z; row[4*i+3] = v.w;
        }
        float oa[D_HID], orr[D_HID];
#pragma unroll
        for (int o = 0; o < D_HID; o++) {
            float a = 0.f, r = s_b[o];
#pragma unroll
            for (int k = 0; k < D_IN; k++) {
                a += row[k] * s_rel[o * D_IN + k];
                r += row[k] * s_root[o * D_IN + k];
            }
            oa[o] = a; orr[o] = r;
        }
        unsigned p[8];
#pragma unroll
        for (int i = 0; i < 8; i++)
            p[i] = bfr(oa[2*i]) | (bfr(oa[2*i+1]) << 16);
        uint4* xrp = (uint4*)(xr + (size_t)node * D_HID);
        xrp[0] = make_uint4(p[0], p[1], p[2], p[3]);
        xrp[1] = make_uint4(p[4], p[5], p[6], p[7]);
        float4* aggp = (float4*)(aggr + (size_t)node * D_HID);
#pragma unroll
        for (int i = 0; i < D_HID / 4; i++)
            aggp[i] = make_float4(orr[4*i], orr[4*i+1], orr[4*i+2], orr[4*i+3]);
    }
    __syncthreads();

    // ---- phase C: scan (wave 0) || global reservation (waves 1-7) ----
    if (tid < 64) {
        int running = 0;
        for (int c = 0; c < (NB + 63) / 64; c++) {
            int idx = c * 64 + tid;
            int v = (idx < NB) ? cnt[idx] : 0;
            int incl = v;
#pragma unroll
            for (int off = 1; off < 64; off <<= 1) {
                int t = __shfl_up(incl, off);
                if (tid >= off) incl += t;
            }
            if (idx < NB) loff[idx] = running + incl - v;
            running += __shfl(incl, 63);
        }
    } else {
        for (int i = tid - 64; i < NB; i += 448)
            gbase[i] = (cnt[i] > 0) ? atomicAdd(&gcur[i], cnt[i]) : 0;
    }
    __syncthreads();

    // ---- phase D1: placement; store rec + final global slot ----
    for (int e = e0 + tid; e < e1; e += 512) {
        int src = ei[e];
        int dst = ei[N_EDGES + e];
        int bkt = dst >> 7;
        int r = atomicAdd(&lcnt[bkt], 1);
        int p = loff[bkt] + r;
        int gslot = gbase[bkt] + r;
        sorted[p] = ((unsigned)(dst & (NPB - 1)) << 17) | (unsigned)src;
        gidx[p] = (gslot < PBC) ? (bkt * PBC + gslot) : -1;  // overflow guard
    }
    __syncthreads();

    // ---- phase D2: linear write-out (coalesced runs per bucket) ----
    int n4 = e1 - e0;
    for (int i = tid; i < n4; i += 512) {
        int s = gidx[i];
        if (s >= 0) recs2[s] = sorted[i];
    }
}

// ---------------------------------------------------------------------------
// Fused per-bucket sort + layer-1 accumulate + node-2 epilogue:
//  1. stage the bucket window in LDS (coalesced read)
//  2. counting-sort by (dst&127) into a second LDS array, pad to 16
//  3. write sorted records back coalesced (consumed later by k_acc2)
//  4. accumulate: 32 groups x 16 lanes, 16-record register chunks from LDS,
//     run-combining, flush runs into a 128x17 LDS tile (16 consecutive
//     banks per flush — conflict-free; block owns all its 128 dsts)
//  5. epilogue per node (tid < 128): h = relu(aggr_row + tile_row);
//     hr = h @ w2_rel^T ; out = h @ w2_root^T + b2.
// ---------------------------------------------------------------------------
__global__ __launch_bounds__(512) void k_sortacc(
    const int* __restrict__ gcur, unsigned* __restrict__ recs2,
    const unsigned short* __restrict__ srcf, const float* __restrict__ aggr,
    const float* __restrict__ w2rel, const float* __restrict__ w2root,
    const float* __restrict__ b2,
    float* __restrict__ hr, float* __restrict__ outv)
{
    __shared__ unsigned stage[PBC];
    __shared__ unsigned sorted[PBC];
    __shared__ float tile[NPB * 17];             // 8.7 KB, bank-padded
    __shared__ int hist[NPB], sc[NPB], cur[NPB];
    __shared__ float s_rel[D_OUT * D_HID];
    __shared__ float s_root[D_OUT * D_HID];
    __shared__ float s_b2[D_OUT];
    int b = blockIdx.x, tid = threadIdx.x;
    int n = min(gcur[b], PBC);
    unsigned* w = recs2 + (size_t)b * PBC;

    if (tid < NPB) hist[tid] = 0;
    if (tid < D_OUT * D_HID) {
        s_rel[tid]  = w2rel[tid];
        s_root[tid] = w2root[tid];
    }
    if (tid < D_OUT) s_b2[tid] = b2[tid];
    for (int i = tid; i < NPB * 17; i += 512) tile[i] = 0.f;
    for (int i = tid; i < n; i += 512) stage[i] = w[i];
    __syncthreads();
    for (int i = tid; i < n; i += 512)
        atomicAdd(&hist[stage[i] >> 17], 1);
    __syncthreads();
    if (tid < NPB) sc[tid] = hist[tid];
    __syncthreads();
#pragma unroll
    for (int off = 1; off < NPB; off <<= 1) {
        int t = (tid >= off && tid < NPB) ? sc[tid - off] : 0;
        __syncthreads();
        if (tid < NPB) sc[tid] += t;
        __syncthreads();
    }
    if (tid < NPB) cur[tid] = sc[tid] - hist[tid];
    __syncthreads();
    for (int i = tid; i < n; i += 512) {
        unsigned r = stage[i];
        int slot = atomicAdd(&cur[r >> 17], 1);
        sorted[slot] = r;
    }
    int npad = (n + PAD_ALIGN - 1) & ~(PAD_ALIGN - 1);
    for (int i = n + tid; i < npad; i += 512) sorted[i] = DUMMY_REC;
    __syncthreads();

    // write back sorted (sequential, coalesced) for k_acc2
    for (int i = tid; i < npad; i += 512) w[i] = sorted[i];

    // layer-1 accumulate from LDS, flushing runs into the LDS tile
    int g = tid >> 4;                 // 0..31
    int f = tid & (D_HID - 1);
    for (int base = g * 16; base < npad; base += 32 * 16) {
        unsigned e[16];
#pragma unroll
        for (int k = 0; k < 16; k++) e[k] = sorted[base + k];
        float v[16];
#pragma unroll
        for (int k = 0; k < 16; k++)
            v[k] = bfu(srcf[(e[k] & 0x1FFFF) * D_HID + f]);

        unsigned curd = e[0] >> 17;
        float acc = v[0];
#pragma unroll
        for (int k = 1; k < 16; k++) {
            unsigned dl = e[k] >> 17;
            if (dl == curd) {
                acc += v[k];
            } else {
                atomicAdd(&tile[curd * 17 + f], acc);
                curd = dl;
                acc = v[k];
            }
        }
        atomicAdd(&tile[curd * 17 + f], acc);
    }
    __syncthreads();

    // node-2 epilogue: 128 nodes, one thread each
    if (tid < NPB) {
        int node = b * NPB + tid;
        if (node < N_NODES) {
            float hv[D_HID];
            const float4* ap = (const float4*)(aggr + (size_t)node * D_HID);
#pragma unroll
            for (int i = 0; i < D_HID / 4; i++) {
                float4 r = ap[i];
                hv[4*i+0] = fmaxf(r.x + tile[tid * 17 + 4*i+0], 0.f);
                hv[4*i+1] = fmaxf(r.y + tile[tid * 17 + 4*i+1], 0.f);
                hv[4*i+2] = fmaxf(r.z + tile[tid * 17 + 4*i+2], 0.f);
                hv[4*i+3] = fmaxf(r.w + tile[tid * 17 + 4*i+3], 0.f);
            }
            float o_rel[D_OUT], o_root[D_OUT];
#pragma unroll
            for (int o = 0; o < D_OUT; o++) {
                float a = 0.f, r = s_b2[o];
#pragma unroll
                for (int k = 0; k < D_HID; k++) {
                    a += hv[k] * s_rel[o * D_HID + k];
                    r += hv[k] * s_root[o * D_HID + k];
                }
                o_rel[o] = a; o_root[o] = r;
            }
            ((float2*)hr)[node]   = make_float2(o_rel[0], o_rel[1]);
            ((float2*)outv)[node] = make_float2(o_root[0], o_root[1]);
        }
    }
    // dummy hr rows (N_NODES..NROWS) for DUMMY_SRC gathers:
    if (b == NB - 1 && tid >= NPB && tid < NPB + 8) {
        int node = N_NODES + (tid - NPB);
        if (node < NROWS) ((float2*)hr)[node] = make_float2(0.f, 0.f);
    }
}

// ---------------------------------------------------------------------------
// Layer-2 accumulate: 2 lanes/record, ACC2_K=16 records/group, float2 hr
// gathers (0.8 MB, L2-resident), run-combining, flushes straight into out.
// Bounds-guarded for dummy/tail records.
// ---------------------------------------------------------------------------
__global__ __launch_bounds__(256) void k_acc2(
    const unsigned* __restrict__ recs2, const int* __restrict__ gcur,
    const float* __restrict__ hr, float* __restrict__ outv)
{
    int bucket = blockIdx.x / ACC2_BPB;
    int blk    = blockIdx.x % ACC2_BPB;
    int g = threadIdx.x >> 1;
    int f = threadIdx.x & 1;
    int r0 = (blk * 128 + g) * ACC2_K;
    int n = min(gcur[bucket], PBC);
    if (r0 >= n) return;
    const unsigned* rp = recs2 + (size_t)bucket * PBC + r0;

    unsigned e[ACC2_K];
#pragma unroll
    for (int k = 0; k < ACC2_K; k++) e[k] = rp[k];
    float v[ACC2_K];
#pragma unroll
    for (int k = 0; k < ACC2_K; k++)
        v[k] = hr[(e[k] & 0x1FFFF) * D_OUT + f];

    int dbase = bucket * NPB;
    unsigned cur = e[0] >> 17;
    float acc = v[0];
#pragma unroll
    for (int k = 1; k < ACC2_K; k++) {
        unsigned dl = e[k] >> 17;
        if (dl == cur) {
            acc += v[k];
        } else {
            int d = dbase + (int)cur;
            if (d < N_NODES) atomicAdd(&outv[d * D_OUT + f], acc);
            cur = dl;
            acc = v[k];
        }
    }
    int d = dbase + (int)cur;
    if (d < N_NODES) atomicAdd(&outv[d * D_OUT + f], acc);
}

extern "C" void kernel_launch(void* const* d_in, const int* in_sizes, int n_in,
                              void* d_out, int out_size, void* d_ws, size_t ws_size,
                              hipStream_t stream) {
    const float* x       = (const float*)d_in[0];
    const int*   ei      = (const int*)  d_in[1];
    const float* w1_rel  = (const float*)d_in[2];
    const float* w1_root = (const float*)d_in[3];
    const float* b1      = (const float*)d_in[4];
    const float* w2_rel  = (const float*)d_in[5];
    const float* w2_root = (const float*)d_in[6];
    const float* b2      = (const float*)d_in[7];
    float* out = (float*)d_out;

    // Workspace (~18.5 MB; everything rewritten each call):
    float*          aggr  = (float*)d_ws;                                   // NROWS*16 f32 (6.4 MB, root term only)
    unsigned short* xrh   = (unsigned short*)(aggr + (size_t)NROWS * D_HID);// NROWS*16 bf16 (3.2 MB)
    unsigned*       recs2 = (unsigned*)(xrh + (size_t)NROWS * D_HID);       // NB*PBC (8.0 MB)
    float*          hr    = (float*)(recs2 + (size_t)NB * PBC);             // NROWS*2 f32 (0.8 MB)
    int*            gcur  = (int*)(hr + (size_t)NROWS * D_OUT);             // NB

    hipMemsetAsync(gcur, 0, NB * sizeof(int), stream);

    k_bin_node1<<<dim3(BBLOCKS), dim3(512), 0, stream>>>(
        ei, x, w1_rel, w1_root, b1, xrh, aggr, gcur, recs2);

    k_sortacc<<<dim3(NB), dim3(512), 0, stream>>>(
        gcur, recs2, xrh, aggr, w2_rel, w2_root, b2, hr, out);

    k_acc2<<<dim3(ACC2_BLOCKS), dim3(256), 0, stream>>>(recs2, gcur, hr, out);
}

// Round 20
// 162.751 us; speedup vs baseline: 1.0333x; 1.0333x over previous
//
#include <hip/hip_runtime.h>

#define N_NODES 100000
#define N_EDGES 1600000
#define D_IN 32
#define D_HID 16
#define D_OUT 2

// dst bucketing: 128 nodes per bucket.
#define NPB 128
#define NB 782                       // ceil(100000/128)
#define NROWS (NB * NPB)             // 100096 padded feature rows
#define CHUNK 4096
#define BBLOCKS ((N_EDGES + CHUNK - 1) / CHUNK)   // 391

// Padded per-bucket record windows (mean fill 2046, 11 sigma headroom).
#define PBC 2560
#define DUMMY_SRC 100000u            // zeroed xr feature row
#define DUMMY_REC ((127u << 17) | DUMMY_SRC)
#define PAD_ALIGN 16

// Layer-2 acc: 2 lanes/record, ACC2_K records per group, 128 groups/block.
#define ACC2_K 16
#define ACC2_BPB 2                     // 2*128*16 = 4096 slots >= PBC
#define ACC2_BLOCKS (NB * ACC2_BPB)    // 1564

__device__ __forceinline__ unsigned bfr(float x) {   // f32 -> bf16 (RNE)
    unsigned u = __float_as_uint(x);
    return (u + 0x7FFFu + ((u >> 16) & 1u)) >> 16;
}
__device__ __forceinline__ float bfu(unsigned lo16) {
    return __uint_as_float(lo16 << 16);
}

// ---------------------------------------------------------------------------
// Fused bin + node-1 transform with bucket-grouped coalesced write-out:
//  A. LDS histogram of the block's 4096-edge chunk
//  B. node-1 dense transform (overlapped; VALU hides A's latency)
//  C. (wave 0) shuffle-scan cnt -> loff  ||  (waves 1-7) global cursor
//     reservation -> gbase
//  D1. placement: rank each record (LDS atomic), group by bucket in LDS
//  D2. linear write-out: consecutive lanes hit consecutive window slots
// ---------------------------------------------------------------------------
__global__ __launch_bounds__(512) void k_bin_node1(
    const int* __restrict__ ei, const float* __restrict__ x,
    const float* __restrict__ w_rel, const float* __restrict__ w_root,
    const float* __restrict__ bb,
    unsigned short* __restrict__ xr, float* __restrict__ agg,
    int* __restrict__ gcur, unsigned* __restrict__ recs2)
{
    __shared__ int cnt[NB];
    __shared__ int lcnt[NB];
    __shared__ int loff[NB];
    __shared__ int gbase[NB];
    __shared__ unsigned sorted[CHUNK];           // 16 KB
    __shared__ unsigned short bkt16[CHUNK];      // 8 KB
    __shared__ float s_rel[D_HID * D_IN];
    __shared__ float s_root[D_HID * D_IN];
    __shared__ float s_b[D_HID];
    int blk = blockIdx.x, tid = threadIdx.x;

    for (int i = tid; i < D_HID * D_IN; i += 512) {
        s_rel[i]  = w_rel[i];
        s_root[i] = w_root[i];
    }
    if (tid < D_HID) s_b[tid] = bb[tid];
    for (int i = tid; i < NB; i += 512) { cnt[i] = 0; lcnt[i] = 0; }
    __syncthreads();

    // ---- phase A: histogram ----
    int e0 = blk * CHUNK;
    int e1 = min(e0 + CHUNK, N_EDGES);
    for (int e = e0 + tid; e < e1; e += 512)
        atomicAdd(&cnt[ei[N_EDGES + e] >> 7], 1);

    // ---- phase B: node-1 transform (independent of A) ----
    int node = blk * 512 + tid;                    // 391*512 = 200192 > 100001
    if (node == N_NODES) {                         // dummy zero xr row
        uint4* xp = (uint4*)(xr + (size_t)node * D_HID);
        xp[0] = make_uint4(0, 0, 0, 0);
        xp[1] = make_uint4(0, 0, 0, 0);
    } else if (node < N_NODES) {
        float row[D_IN];
        const float4* xp = (const float4*)(x + (size_t)node * D_IN);
#pragma unroll
        for (int i = 0; i < D_IN / 4; i++) {
            float4 v = xp[i];
            row[4*i+0] = v.x; row[4*i+1] = v.y; row[4*i+2] = v.z; row[4*i+3] = v.w;
        }
        float oa[D_HID], orr[D_HID];
#pragma unroll
        for (int o = 0; o < D_HID; o++) {
            float a = 0.f, r = s_b[o];
#pragma unroll
            for (int k = 0; k < D_IN; k++) {
                a += row[k] * s_rel[o * D_IN + k];
                r += row[k] * s_root[o * D_IN + k];
            }
            oa[o] = a; orr[o] = r;
        }
        unsigned p[8];
#pragma unroll
        for (int i = 0; i < 8; i++)
            p[i] = bfr(oa[2*i]) | (bfr(oa[2*i+1]) << 16);
        uint4* xrp = (uint4*)(xr + (size_t)node * D_HID);
        xrp[0] = make_uint4(p[0], p[1], p[2], p[3]);
        xrp[1] = make_uint4(p[4], p[5], p[6], p[7]);
        float4* aggp = (float4*)(agg + (size_t)node * D_HID);
#pragma unroll
        for (int i = 0; i < D_HID / 4; i++)
            aggp[i] = make_float4(orr[4*i], orr[4*i+1], orr[4*i+2], orr[4*i+3]);
    }
    __syncthreads();

    // ---- phase C: scan (wave 0) || global reservation (waves 1-7) ----
    if (tid < 64) {
        int running = 0;
        for (int c = 0; c < (NB + 63) / 64; c++) {
            int idx = c * 64 + tid;
            int v = (idx < NB) ? cnt[idx] : 0;
            int incl = v;
#pragma unroll
            for (int off = 1; off < 64; off <<= 1) {
                int t = __shfl_up(incl, off);
                if (tid >= off) incl += t;
            }
            if (idx < NB) loff[idx] = running + incl - v;
            running += __shfl(incl, 63);
        }
    } else {
        for (int i = tid - 64; i < NB; i += 448)
            gbase[i] = (cnt[i] > 0) ? atomicAdd(&gcur[i], cnt[i]) : 0;
    }
    __syncthreads();

    // ---- phase D1: placement, grouped by bucket in LDS ----
    for (int e = e0 + tid; e < e1; e += 512) {
        int src = ei[e];
        int dst = ei[N_EDGES + e];
        int bkt = dst >> 7;
        int r = atomicAdd(&lcnt[bkt], 1);
        int p = loff[bkt] + r;
        sorted[p] = ((unsigned)(dst & (NPB - 1)) << 17) | (unsigned)src;
        bkt16[p] = (unsigned short)bkt;
    }
    __syncthreads();

    // ---- phase D2: linear write-out (coalesced runs per bucket) ----
    int n4 = e1 - e0;
    for (int i = tid; i < n4; i += 512) {
        int b = bkt16[i];
        int idx = gbase[b] + (i - loff[b]);
        if (idx < PBC)                             // 11-sigma overflow guard
            recs2[b * PBC + idx] = sorted[i];
    }
}

// ---------------------------------------------------------------------------
// Fused per-bucket sort + layer-1 accumulate:
//  1. stage the bucket window in LDS (coalesced read)
//  2. counting-sort by (dst&127) into a second LDS array, pad to 16
//  3. write sorted records back coalesced (consumed later by k_acc2)
//  4. accumulate: 32 groups x 16 lanes, 16-record register chunks from LDS,
//     16 independent bf16 line-gathers in flight, run-combining, atomic
//     flush into agg (~200 flushes/bucket).
// ---------------------------------------------------------------------------
__global__ __launch_bounds__(512) void k_sortacc(
    const int* __restrict__ gcur, unsigned* __restrict__ recs2,
    const unsigned short* __restrict__ srcf, float* __restrict__ dstf)
{
    __shared__ unsigned stage[PBC];
    __shared__ unsigned sorted[PBC];
    __shared__ int hist[NPB], sc[NPB], cur[NPB];
    int b = blockIdx.x, tid = threadIdx.x;
    int n = min(gcur[b], PBC);
    unsigned* w = recs2 + (size_t)b * PBC;

    if (tid < NPB) hist[tid] = 0;
    for (int i = tid; i < n; i += 512) stage[i] = w[i];
    __syncthreads();
    for (int i = tid; i < n; i += 512)
        atomicAdd(&hist[stage[i] >> 17], 1);
    __syncthreads();
    if (tid < NPB) sc[tid] = hist[tid];
    __syncthreads();
#pragma unroll
    for (int off = 1; off < NPB; off <<= 1) {
        int t = (tid >= off && tid < NPB) ? sc[tid - off] : 0;
        __syncthreads();
        if (tid < NPB) sc[tid] += t;
        __syncthreads();
    }
    if (tid < NPB) cur[tid] = sc[tid] - hist[tid];
    __syncthreads();
    for (int i = tid; i < n; i += 512) {
        unsigned r = stage[i];
        int slot = atomicAdd(&cur[r >> 17], 1);
        sorted[slot] = r;
    }
    int npad = (n + PAD_ALIGN - 1) & ~(PAD_ALIGN - 1);
    for (int i = n + tid; i < npad; i += 512) sorted[i] = DUMMY_REC;
    __syncthreads();

    // write back sorted (sequential, coalesced) for k_acc2
    for (int i = tid; i < npad; i += 512) w[i] = sorted[i];

    // layer-1 accumulate straight from LDS
    int g = tid >> 4;                 // 0..31
    int f = tid & (D_HID - 1);
    int dbase = b * NPB;
    for (int base = g * 16; base < npad; base += 32 * 16) {
        unsigned e[16];
#pragma unroll
        for (int k = 0; k < 16; k++) e[k] = sorted[base + k];
        float v[16];
#pragma unroll
        for (int k = 0; k < 16; k++)
            v[k] = bfu(srcf[(e[k] & 0x1FFFF) * D_HID + f]);

        unsigned curd = e[0] >> 17;
        float acc = v[0];
#pragma unroll
        for (int k = 1; k < 16; k++) {
            unsigned dl = e[k] >> 17;
            if (dl == curd) {
                acc += v[k];
            } else {
                atomicAdd(&dstf[(dbase + curd) * D_HID + f], acc);
                curd = dl;
                acc = v[k];
            }
        }
        atomicAdd(&dstf[(dbase + curd) * D_HID + f], acc);
    }
}

// ---------------------------------------------------------------------------
// Fold layer-2 weights per node:  h = relu(agg1);
//   hr[i]  = h @ w2_rel^T   (float2; gathered by k_acc2)
//   out[i] = h @ w2_root^T + b2   (accumulator init, written directly)
// ---------------------------------------------------------------------------
__global__ __launch_bounds__(256) void k_node2h(
    const float* __restrict__ agg,
    const float* __restrict__ w_rel, const float* __restrict__ w_root,
    const float* __restrict__ b,
    float* __restrict__ hr, float* __restrict__ outv)
{
    __shared__ float s_rel[D_OUT * D_HID];
    __shared__ float s_root[D_OUT * D_HID];
    __shared__ float s_b[D_OUT];
    if (threadIdx.x < D_OUT * D_HID) {
        s_rel[threadIdx.x]  = w_rel[threadIdx.x];
        s_root[threadIdx.x] = w_root[threadIdx.x];
    }
    if (threadIdx.x < D_OUT) s_b[threadIdx.x] = b[threadIdx.x];
    __syncthreads();

    int node = blockIdx.x * blockDim.x + threadIdx.x;
    if (node > N_NODES) return;
    if (node == N_NODES) {
        ((float2*)hr)[node] = make_float2(0.f, 0.f);
        return;
    }

    float hv[D_HID];
    const float4* ap = (const float4*)(agg + (size_t)node * D_HID);
#pragma unroll
    for (int i = 0; i < D_HID / 4; i++) {
        float4 v = ap[i];
        hv[4*i+0] = fmaxf(v.x, 0.f); hv[4*i+1] = fmaxf(v.y, 0.f);
        hv[4*i+2] = fmaxf(v.z, 0.f); hv[4*i+3] = fmaxf(v.w, 0.f);
    }

    float o_rel[D_OUT], o_root[D_OUT];
#pragma unroll
    for (int o = 0; o < D_OUT; o++) {
        float a = 0.f, r = s_b[o];
#pragma unroll
        for (int k = 0; k < D_HID; k++) {
            a += hv[k] * s_rel[o * D_HID + k];
            r += hv[k] * s_root[o * D_HID + k];
        }
        o_rel[o] = a; o_root[o] = r;
    }
    ((float2*)hr)[node]   = make_float2(o_rel[0], o_rel[1]);
    ((float2*)outv)[node] = make_float2(o_root[0], o_root[1]);
}

// ---------------------------------------------------------------------------
// Layer-2 accumulate: 2 lanes/record, ACC2_K=16 records/group, float2 hr
// gathers (0.8 MB, L2-resident), run-combining, flushes straight into out.
// Dummy/tail recs map to row >= N_NODES in last bucket -> bounds-guarded;
// elsewhere they contribute hr[DUMMY_SRC] = 0.
// ---------------------------------------------------------------------------
__global__ __launch_bounds__(256) void k_acc2(
    const unsigned* __restrict__ recs2, const int* __restrict__ gcur,
    const float* __restrict__ hr, float* __restrict__ outv)
{
    int bucket = blockIdx.x / ACC2_BPB;
    int blk    = blockIdx.x % ACC2_BPB;
    int g = threadIdx.x >> 1;
    int f = threadIdx.x & 1;
    int r0 = (blk * 128 + g) * ACC2_K;
    int n = min(gcur[bucket], PBC);
    if (r0 >= n) return;
    const unsigned* rp = recs2 + (size_t)bucket * PBC + r0;

    unsigned e[ACC2_K];
#pragma unroll
    for (int k = 0; k < ACC2_K; k++) e[k] = rp[k];
    float v[ACC2_K];
#pragma unroll
    for (int k = 0; k < ACC2_K; k++)
        v[k] = hr[(e[k] & 0x1FFFF) * D_OUT + f];

    int dbase = bucket * NPB;
    unsigned cur = e[0] >> 17;
    float acc = v[0];
#pragma unroll
    for (int k = 1; k < ACC2_K; k++) {
        unsigned dl = e[k] >> 17;
        if (dl == cur) {
            acc += v[k];
        } else {
            int d = dbase + (int)cur;
            if (d < N_NODES) atomicAdd(&outv[d * D_OUT + f], acc);
            cur = dl;
            acc = v[k];
        }
    }
    int d = dbase + (int)cur;
    if (d < N_NODES) atomicAdd(&outv[d * D_OUT + f], acc);
}

extern "C" void kernel_launch(void* const* d_in, const int* in_sizes, int n_in,
                              void* d_out, int out_size, void* d_ws, size_t ws_size,
                              hipStream_t stream) {
    const float* x       = (const float*)d_in[0];
    const int*   ei      = (const int*)  d_in[1];
    const float* w1_rel  = (const float*)d_in[2];
    const float* w1_root = (const float*)d_in[3];
    const float* b1      = (const float*)d_in[4];
    const float* w2_rel  = (const float*)d_in[5];
    const float* w2_root = (const float*)d_in[6];
    const float* b2      = (const float*)d_in[7];
    float* out = (float*)d_out;

    // Workspace (~18.5 MB; everything rewritten each call):
    float*          agg   = (float*)d_ws;                                   // NROWS*16 f32 (6.4 MB)
    unsigned short* xrh   = (unsigned short*)(agg + (size_t)NROWS * D_HID); // NROWS*16 bf16 (3.2 MB)
    unsigned*       recs2 = (unsigned*)(xrh + (size_t)NROWS * D_HID);       // NB*PBC (8.0 MB)
    float*          hr    = (float*)(recs2 + (size_t)NB * PBC);             // NROWS*2 f32 (0.8 MB)
    int*            gcur  = (int*)(hr + (size_t)NROWS * D_OUT);             // NB

    hipMemsetAsync(gcur, 0, NB * sizeof(int), stream);

    k_bin_node1<<<dim3(BBLOCKS), dim3(512), 0, stream>>>(
        ei, x, w1_rel, w1_root, b1, xrh, agg, gcur, recs2);

    k_sortacc<<<dim3(NB), dim3(512), 0, stream>>>(gcur, recs2, xrh, agg);

    k_node2h<<<dim3((N_NODES + 256) / 256), dim3(256), 0, stream>>>(
        agg, w2_rel, w2_root, b2, hr, out);

    k_acc2<<<dim3(ACC2_BLOCKS), dim3(256), 0, stream>>>(recs2, gcur, hr, out);
}